// Round 12
// baseline (249.781 us; speedup 1.0000x reference)
//
#include <hip/hip_runtime.h>
#include <math.h>

// PerceptronGlia r12: split-row, packed-FP32.
// One 128-thread block (2 waves) owns 2 rows packed as float2 (A=.x,B=.y).
// Wave 0 owns positions [0, 64K) (own [0,H) + 64-wide ghost), wave 1 owns
// [H, 128K-64), H = 64K-64. The 3-tap scan propagates right->left only, so
// only wave0 needs ghost; ghost degrades 2/layer and each <=32-layer phase
// ends with an LDS repack that doubles as the ghost refresh (no extra syncs).
// 4096 waves -> 4 waves/SIMD (2x r11's TLP) at ~1.08x issue.
// Weights pre-transposed to d_ws: [phase][layer][wave][chunk][lane][float4].

#define G 2

// ---- packed-FP32 asm helpers (weight broadcast via op_sel) ----
template<int HI>
__device__ __forceinline__ float2 pk_mul_b(float2 a, float2 w) {
    float2 d;
    if constexpr (HI)
        asm("v_pk_mul_f32 %0, %1, %2 op_sel:[0,1] op_sel_hi:[1,1]"
            : "=v"(d) : "v"(a), "v"(w));
    else
        asm("v_pk_mul_f32 %0, %1, %2 op_sel_hi:[1,0]"
            : "=v"(d) : "v"(a), "v"(w));
    return d;
}
template<int HI>
__device__ __forceinline__ float2 pk_fma_b(float2 a, float2 w, float2 c) {
    float2 d;
    if constexpr (HI)
        asm("v_pk_fma_f32 %0, %1, %2, %3 op_sel:[0,1,0] op_sel_hi:[1,1,1]"
            : "=v"(d) : "v"(a), "v"(w), "v"(c));
    else
        asm("v_pk_fma_f32 %0, %1, %2, %3 op_sel_hi:[1,0,1]"
            : "=v"(d) : "v"(a), "v"(w), "v"(c));
    return d;
}
__device__ __forceinline__ float2 pk_mul2(float2 a, float2 b) {
    float2 d;
    asm("v_pk_mul_f32 %0, %1, %2" : "=v"(d) : "v"(a), "v"(b));
    return d;
}
__device__ __forceinline__ float vexp2(float x) {
    float d;
    asm("v_exp_f32 %0, %1" : "=v"(d) : "v"(x));
    return d;
}

__device__ __forceinline__ float elu_f(float a) {
    return a > 0.0f ? a : (__expf(a) - 1.0f);
}

// ---- one slot of a scan layer, both rows packed; static recursion ----
template<int K, int I, int NW>
__device__ __forceinline__ void slot_run(float2 (&h)[K], const float2 (&w)[NW],
                                         float2 e0, float2 e1, float2 l2e) {
    if constexpr (I < K) {
        float2 x1, x2;
        if constexpr (I + 1 < K) x1 = h[I + 1]; else x1 = e0;
        if constexpr (I + 2 < K) x2 = h[I + 2];
        else if constexpr (I + 2 == K) x2 = e0;
        else x2 = e1;
        float2 acc = pk_mul_b<(3 * I + 2) & 1>(x2, w[(3 * I + 2) >> 1]);
        acc = pk_fma_b<(3 * I + 1) & 1>(x1, w[(3 * I + 1) >> 1], acc);
        acc = pk_fma_b<(3 * I) & 1>(h[I], w[(3 * I) >> 1], acc);
        float2 t = pk_mul2(acc, l2e);
        float ex = vexp2(t.x) - 1.0f;
        float ey = vexp2(t.y) - 1.0f;
        h[I].x = acc.x > 0.0f ? acc.x : ex;
        h[I].y = acc.y > 0.0f ? acc.y : ey;
        slot_run<K, I + 1, NW>(h, w, e0, e1, l2e);
    }
}

template<int K, int NW>
__device__ __forceinline__ void scan_layer_pk(float2 (&h)[K], const float2 (&w)[NW],
                                              float2 l2e) {
    float2 e0, e1;
    e0.x = __shfl_down(h[0].x, 1); e0.y = __shfl_down(h[0].y, 1);
    if constexpr (K >= 2) { e1.x = __shfl_down(h[1].x, 1); e1.y = __shfl_down(h[1].y, 1); }
    else                  { e1.x = __shfl_down(h[0].x, 2); e1.y = __shfl_down(h[0].y, 2); }
    slot_run<K, 0, NW>(h, w, e0, e1, l2e);
}

// ---- transposed-weight load: NC float4 (stride LS float4/layer) ----
template<int NC, int LS>
__device__ __forceinline__ void load_wt2(float2 (&w)[2 * NC], const float4* __restrict__ Tp,
                                         int lr) {
#pragma unroll
    for (int c = 0; c < NC; ++c) {
        float4 v = Tp[(size_t)lr * LS + c * 64];
        w[2 * c]     = make_float2(v.x, v.y);
        w[2 * c + 1] = make_float2(v.z, v.w);
    }
}

// ---- scan phase: depth-3 ring, unconditional prefetch (overshoot <=2 layers,
//      lands in next phase's region / final pad, never consumed) ----
template<int K, int NC, int NL>
__device__ __forceinline__ void scan_phase_split(const float* __restrict__ Tphase,
                                                 int w, int lane, float2 (&h)[K],
                                                 float2 l2e) {
    static_assert(NL >= 3, "ring needs >=3 layers");
    constexpr int LS = 2 * NC * 64;   // float4 per layer (2 waves)
    const float4* __restrict__ Tp =
        reinterpret_cast<const float4*>(Tphase) + (size_t)w * (NC * 64) + lane;
    float2 w0[2 * NC], w1[2 * NC], w2[2 * NC];
    load_wt2<NC, LS>(w0, Tp, 0);
    load_wt2<NC, LS>(w1, Tp, 1);
    load_wt2<NC, LS>(w2, Tp, 2);
    int l = 0;
    for (; l + 3 <= NL; l += 3) {
        scan_layer_pk<K>(h, w0, l2e);  load_wt2<NC, LS>(w0, Tp, l + 3);
        scan_layer_pk<K>(h, w1, l2e);  load_wt2<NC, LS>(w1, Tp, l + 4);
        scan_layer_pk<K>(h, w2, l2e);  load_wt2<NC, LS>(w2, Tp, l + 5);
    }
    if constexpr (NL % 3 >= 1) scan_layer_pk<K>(h, w0, l2e);
    if constexpr (NL % 3 >= 2) scan_layer_pk<K>(h, w1, l2e);
}

// ---- repack KA -> KB through LDS; doubles as wave0's ghost refresh.
// wave0 writes only its valid region [0, HA); wave1 writes all its range. ----
template<int KA, int KB>
__device__ __forceinline__ void repack_split(float2 (&a)[KA], float2 (&n)[KB],
                                             float2* lds, int w, int lane) {
    constexpr int HA = 64 * KA - 64;
    constexpr int HB = 64 * KB - 64;
    __syncthreads();
    int p0 = w * HA + KA * lane;
#pragma unroll
    for (int i = 0; i < KA; ++i) {
        int p = p0 + i;
        if (w == 1 || p < HA) lds[p] = a[i];
    }
    __syncthreads();
    int q0 = w * HB + KB * lane;
#pragma unroll
    for (int i = 0; i < KB; ++i) n[i] = lds[q0 + i];
}

// ---- final 10 logits + log-softmax for one row (K=1: position = lane) ----
__device__ __forceinline__ void emit_row(float v, const float* __restrict__ Wl,
                                         float* __restrict__ out, int row, int lane) {
    float n1 = __shfl_down(v, 1);
    float n2 = __shfl_down(v, 2);
    float lg = 0.0f;
    if (lane < 10)
        lg = fmaf(v, Wl[3 * lane], fmaf(n1, Wl[3 * lane + 1], n2 * Wl[3 * lane + 2]));
    float t = (lane < 10) ? lg : -1e30f;
#pragma unroll
    for (int d = 1; d < 16; d <<= 1) t = fmaxf(t, __shfl_xor(t, d));
    float e = (lane < 10) ? __expf(lg - t) : 0.0f;
    float s = e;
#pragma unroll
    for (int d = 1; d < 16; d <<= 1) s += __shfl_xor(s, d);
    float lse = t + __logf(s);
    if (lane < 10) out[(size_t)row * 10 + lane] = lg - lse;
}

// ---- transposed-weight layout: 13 split phases ----
//  S#   base    l0  nl  K NC  src   (scan1: W0 lstride 2346; scan2: W2 762)
//  S0   0        0  32  7  6  W0
//  S1   98304   32  32  7  6  W0
//  S2   196608  64  32  6  5  W0
//  S3   278528  96  32  6  5  W0
//  S4   360448 128  32  5  4  W0
//  S5   425984 160  32  5  4  W0
//  S6   491520 192  32  4  3  W0
//  S7   540672 224  32  4  3  W0
//  S8   589824 256   7  3  3  W0
//  S9   600576   0  32  3  3  W2
//  S10  649728  32  32  2  2  W2
//  S11  682496  64  32  2  2  W2
//  S12  715264  96  25  1  1  W2
#define T_TOTAL 728064
#define T_ALLOC (T_TOTAL + 1024)   // ring overshoot pad (2 layers x 512)

__global__ __launch_bounds__(256)
void reorder_w(const float* __restrict__ W0, const float* __restrict__ W2,
               float* __restrict__ T) {
    int idx = blockIdx.x * 256 + threadIdx.x;
    if (idx >= T_ALLOC) return;
    if (idx >= T_TOTAL) { T[idx] = 0.0f; return; }
    int base, l0, K, NC, s1;
    if      (idx < 98304)  { base = 0;      l0 = 0;   K = 7; NC = 6; s1 = 1; }
    else if (idx < 196608) { base = 98304;  l0 = 32;  K = 7; NC = 6; s1 = 1; }
    else if (idx < 278528) { base = 196608; l0 = 64;  K = 6; NC = 5; s1 = 1; }
    else if (idx < 360448) { base = 278528; l0 = 96;  K = 6; NC = 5; s1 = 1; }
    else if (idx < 425984) { base = 360448; l0 = 128; K = 5; NC = 4; s1 = 1; }
    else if (idx < 491520) { base = 425984; l0 = 160; K = 5; NC = 4; s1 = 1; }
    else if (idx < 540672) { base = 491520; l0 = 192; K = 4; NC = 3; s1 = 1; }
    else if (idx < 589824) { base = 540672; l0 = 224; K = 4; NC = 3; s1 = 1; }
    else if (idx < 600576) { base = 589824; l0 = 256; K = 3; NC = 3; s1 = 1; }
    else if (idx < 649728) { base = 600576; l0 = 0;   K = 3; NC = 3; s1 = 0; }
    else if (idx < 682496) { base = 649728; l0 = 32;  K = 2; NC = 2; s1 = 0; }
    else if (idx < 715264) { base = 682496; l0 = 64;  K = 2; NC = 2; s1 = 0; }
    else                   { base = 715264; l0 = 96;  K = 1; NC = 1; s1 = 0; }
    const float* Wsrc = s1 ? W0 : W2;
    int lstride = s1 ? 2346 : 762;
    int rel  = idx - base;
    int perL = 2 * NC * 256;
    int lr   = rel / perL;
    int r2   = rel - lr * perL;
    int w    = r2 / (NC * 256);
    int r3   = r2 - w * (NC * 256);
    int c    = r3 >> 8;
    int ln   = (r3 >> 2) & 63;
    int f    = r3 & 3;
    int elem = 4 * c + f;
    float v = 0.0f;
    if (elem < 3 * K) {
        int H = 64 * K - 64;
        int b = 3 * (w * H + K * ln);
        if (b + 3 * K > lstride) b = lstride - 3 * K;   // clamped lanes are all-dead
        v = Wsrc[(size_t)(l0 + lr) * lstride + b + elem];
    }
    T[idx] = v;
}

// ---- main kernel: 2 waves per row-pair, split positions ----
__global__ __launch_bounds__(128, 4)
void pg_split(const float* __restrict__ x,  const float* __restrict__ Ws,
              const float* __restrict__ bs, const float* __restrict__ Wlast,
              const float* __restrict__ T,  float* __restrict__ out)
{
    __shared__ float2 lds[832];            // repack/ghost buffer, 6656 B
    const int t    = threadIdx.x;
    const int w    = t >> 6;
    const int lane = t & 63;
    const int rowA = blockIdx.x * G;
    const int rowB = rowA + 1;
    const float2 l2e = make_float2(1.44269504088896340736f, 1.44269504088896340736f);
    const float2 z2  = make_float2(0.0f, 0.0f);

    // x -> S0 layout (K=7, H=384): pos0 = w*384 + 7*lane
    float2 h7[7];
    {
        int p0 = w * 384 + 7 * lane;
#pragma unroll
        for (int i = 0; i < 7; ++i) {
            int p = p0 + i;
            h7[i].x = (p < 784) ? x[(size_t)rowA * 784 + p] : 0.0f;
            h7[i].y = (p < 784) ? x[(size_t)rowB * 784 + p] : 0.0f;
        }
    }

    // ---- scan 1 (263 layers) ----
    scan_phase_split<7, 6, 32>(T + 0,      w, lane, h7, l2e);
    repack_split<7, 7>(h7, h7, lds, w, lane);
    scan_phase_split<7, 6, 32>(T + 98304, w, lane, h7, l2e);
    float2 h6[6]; repack_split<7, 6>(h7, h6, lds, w, lane);
    scan_phase_split<6, 5, 32>(T + 196608, w, lane, h6, l2e);
    repack_split<6, 6>(h6, h6, lds, w, lane);
    scan_phase_split<6, 5, 32>(T + 278528, w, lane, h6, l2e);
    float2 h5[5]; repack_split<6, 5>(h6, h5, lds, w, lane);
    scan_phase_split<5, 4, 32>(T + 360448, w, lane, h5, l2e);
    repack_split<5, 5>(h5, h5, lds, w, lane);
    scan_phase_split<5, 4, 32>(T + 425984, w, lane, h5, l2e);
    float2 h4[4]; repack_split<5, 4>(h5, h4, lds, w, lane);
    scan_phase_split<4, 3, 32>(T + 491520, w, lane, h4, l2e);
    repack_split<4, 4>(h4, h4, lds, w, lane);
    scan_phase_split<4, 3, 32>(T + 540672, w, lane, h4, l2e);
    float2 h3[3]; repack_split<4, 3>(h4, h3, lds, w, lane);
    scan_phase_split<3, 3, 7>(T + 589824, w, lane, h3, l2e);

    // ---- biased layer (width 256) through LDS; K=3/H=128 layout both sides ----
    __syncthreads();
    {
        int p0 = w * 128 + 3 * lane;
#pragma unroll
        for (int i = 0; i < 3; ++i) {
            int p = p0 + i;
            if (w == 1 || p < 128) lds[p] = h3[i];
        }
    }
    __syncthreads();
    {
        int p0 = w * 128 + 3 * lane;
        float2 y[3];
#pragma unroll
        for (int i = 0; i < 3; ++i) {
            int j = p0 + i;
            if (j < 256) {
                float2 hm = (j > 0)   ? lds[j - 1] : z2;
                float2 hc = lds[j];
                float2 hp = (j < 255) ? lds[j + 1] : z2;   // h[256] == 0 (pad)
                float w0 = Ws[3 * j], w1 = Ws[3 * j + 1], w2 = Ws[3 * j + 2];
                float b = bs[j];
                y[i].x = elu_f(fmaf(hm.x, w0, fmaf(hc.x, w1, fmaf(hp.x, w2, b))));
                y[i].y = elu_f(fmaf(hm.y, w0, fmaf(hc.y, w1, fmaf(hp.y, w2, b))));
            } else y[i] = z2;
        }
#pragma unroll
        for (int i = 0; i < 3; ++i) h3[i] = y[i];
    }

    // ---- scan 2 (121 layers) ----
    scan_phase_split<3, 3, 32>(T + 600576, w, lane, h3, l2e);
    float2 h2[2]; repack_split<3, 2>(h3, h2, lds, w, lane);
    scan_phase_split<2, 2, 32>(T + 649728, w, lane, h2, l2e);
    repack_split<2, 2>(h2, h2, lds, w, lane);
    scan_phase_split<2, 2, 32>(T + 682496, w, lane, h2, l2e);
    float2 h1[1]; repack_split<2, 1>(h2, h1, lds, w, lane);
    scan_phase_split<1, 1, 25>(T + 715264, w, lane, h1, l2e);

    if (w == 0) {
        emit_row(h1[0].x, Wlast, out, rowA, lane);
        emit_row(h1[0].y, Wlast, out, rowB, lane);
    }
}

// ---- fallback (direct gather, G=2 single-wave) used only if ws too small ----
template<int K>
__device__ __forceinline__ void scan_layer_s(float (&h)[K], const float (&w)[3 * K]) {
    float e0 = __shfl_down(h[0], 1);
    float e1;
    if constexpr (K >= 2) e1 = __shfl_down(h[1], 1);
    else                  e1 = __shfl_down(h[0], 2);
#pragma unroll
    for (int i = 0; i < K; ++i) {
        float x1 = (i + 1 < K) ? h[i + 1] : e0;
        float x2 = (i + 2 < K) ? h[i + 2] : ((i + 2 == K) ? e0 : e1);
        float a = fmaf(h[i], w[3 * i], fmaf(x1, w[3 * i + 1], x2 * w[3 * i + 2]));
        h[i] = elu_f(a);
    }
}
template<int K>
__device__ __forceinline__ void scan_phase_s(const float* __restrict__ W, int lstride,
                                             int l0, int l1, int lane,
                                             float (&hA)[K], float (&hB)[K]) {
    int base = 3 * K * lane;
    if (base + 3 * K > lstride) base = lstride - 3 * K;
    const float* __restrict__ Wp = W + (size_t)l0 * lstride + base;
    float wa[3 * K];
    for (int l = l0; l < l1; ++l) {
#pragma unroll
        for (int j = 0; j < 3 * K; ++j) wa[j] = Wp[j];
        scan_layer_s<K>(hA, wa);
        scan_layer_s<K>(hB, wa);
        Wp += lstride;
    }
}
template<int KA, int KB>
__device__ __forceinline__ void repack_s(float (&aA)[KA], float (&aB)[KA],
                                         float (&nA)[KB], float (&nB)[KB],
                                         float* lds, int lane) {
    __syncthreads();
#pragma unroll
    for (int i = 0; i < KA; ++i) lds[KA * lane + i] = aA[i];
    __syncthreads();
#pragma unroll
    for (int i = 0; i < KB; ++i) nA[i] = lds[KB * lane + i];
    __syncthreads();
#pragma unroll
    for (int i = 0; i < KA; ++i) lds[KA * lane + i] = aB[i];
    __syncthreads();
#pragma unroll
    for (int i = 0; i < KB; ++i) nB[i] = lds[KB * lane + i];
    __syncthreads();
}
__global__ __launch_bounds__(64)
void pg_kernel_d(const float* __restrict__ x,  const float* __restrict__ W0,
                 const float* __restrict__ Ws, const float* __restrict__ bs,
                 const float* __restrict__ W2, const float* __restrict__ Wlast,
                 float* __restrict__ out)
{
    __shared__ float lds[13 * 64];
    const int lane = threadIdx.x;
    const int rowA = blockIdx.x * 2;
    const int rowB = rowA + 1;
    float a13[13], b13[13];
#pragma unroll
    for (int i = 0; i < 13; ++i) {
        int p = 13 * lane + i;
        a13[i] = (p < 784) ? x[(size_t)rowA * 784 + p] : 0.0f;
        b13[i] = (p < 784) ? x[(size_t)rowB * 784 + p] : 0.0f;
    }
    scan_phase_s<13>(W0, 2346, 0, 71, lane, a13, b13);
    float a10[10], b10[10]; repack_s<13, 10>(a13, b13, a10, b10, lds, lane);
    scan_phase_s<10>(W0, 2346, 71, 167, lane, a10, b10);
    float a7[7], b7[7];     repack_s<10, 7>(a10, b10, a7, b7, lds, lane);
    scan_phase_s<7>(W0, 2346, 167, 231, lane, a7, b7);
    float a5[5], b5[5];     repack_s<7, 5>(a7, b7, a5, b5, lds, lane);
    scan_phase_s<5>(W0, 2346, 231, 263, lane, a5, b5);
    {   // stage2 (both rows)
        float ya[5], yb[5];
        float pa = __shfl_up(a5[4], 1); if (lane == 0) pa = 0.f;
        float pb = __shfl_up(b5[4], 1); if (lane == 0) pb = 0.f;
        float qa = __shfl_down(a5[0], 1);
        float qb = __shfl_down(b5[0], 1);
#pragma unroll
        for (int i = 0; i < 5; ++i) {
            int j = 5 * lane + i;
            bool v = j < 256;
            float w0 = v ? Ws[3 * j] : 0.f, w1 = v ? Ws[3 * j + 1] : 0.f;
            float w2 = v ? Ws[3 * j + 2] : 0.f, b = v ? bs[j] : 0.f;
            float am = (i == 0) ? pa : a5[i - 1];
            float ap = (i == 4) ? qa : a5[i + 1];
            float bm = (i == 0) ? pb : b5[i - 1];
            float bp = (i == 4) ? qb : b5[i + 1];
            float ac = v ? a5[i] : 0.f, bc = v ? b5[i] : 0.f;
            if (!v) { am = ap = bm = bp = 0.f; }
            ya[i] = elu_f(fmaf(am, w0, fmaf(ac, w1, fmaf(ap, w2, b))));
            yb[i] = elu_f(fmaf(bm, w0, fmaf(bc, w1, fmaf(bp, w2, b))));
        }
#pragma unroll
        for (int i = 0; i < 5; ++i) { a5[i] = ya[i]; b5[i] = yb[i]; }
    }
    float a4[4], b4[4];     repack_s<5, 4>(a5, b5, a4, b4, lds, lane);
    scan_phase_s<4>(W2, 762, 0, 31, lane, a4, b4);
    float a3[3], b3[3];     repack_s<4, 3>(a4, b4, a3, b3, lds, lane);
    scan_phase_s<3>(W2, 762, 31, 63, lane, a3, b3);
    float a2_[2], b2_[2];   repack_s<3, 2>(a3, b3, a2_, b2_, lds, lane);
    scan_phase_s<2>(W2, 762, 63, 95, lane, a2_, b2_);
    float a1[1], b1[1];     repack_s<2, 1>(a2_, b2_, a1, b1, lds, lane);
    scan_phase_s<1>(W2, 762, 95, 121, lane, a1, b1);
    emit_row(a1[0], Wlast, out, rowA, lane);
    emit_row(b1[0], Wlast, out, rowB, lane);
}

extern "C" void kernel_launch(void* const* d_in, const int* in_sizes, int n_in,
                              void* d_out, int out_size, void* d_ws, size_t ws_size,
                              hipStream_t stream) {
    const float* x     = (const float*)d_in[0];
    const float* W0    = (const float*)d_in[1];
    const float* Ws    = (const float*)d_in[2];
    const float* bs    = (const float*)d_in[3];
    const float* W2    = (const float*)d_in[4];
    const float* Wlast = (const float*)d_in[5];
    float* out = (float*)d_out;

    if (ws_size >= (size_t)T_ALLOC * sizeof(float)) {
        float* T = (float*)d_ws;
        reorder_w<<<(T_ALLOC + 255) / 256, 256, 0, stream>>>(W0, W2, T);
        pg_split<<<4096 / G, 128, 0, stream>>>(x, Ws, bs, Wlast, T, out);
    } else {
        pg_kernel_d<<<2048, 64, 0, stream>>>(x, W0, Ws, bs, W2, Wlast, out);
    }
}

// Round 16
// 247.030 us; speedup vs baseline: 1.0111x; 1.0111x over previous
//
#include <hip/hip_runtime.h>
#include <math.h>

// PerceptronGlia r16 = r14 resubmit (two infra failures, never ran).
// One 64-thread block (1 wave) owns 2 rows packed as float2 (A=.x, B=.y).
// Lane l owns K consecutive positions; K shrinks at every 64-width boundary
// (13x7,12,11,...,5 x32 for scan-1; 4,3,2,1 for scan-2) with wave-local LDS
// repacks. 3-tap dot via v_pk_fma_f32 with op_sel weight broadcast.
// Change vs r11: depth-2 weight double-buffer with
// __builtin_amdgcn_sched_barrier(0) after each load cluster -- pins
// load(l+1) issue BEFORE compute(l) so the vmcnt wait lands after ~400cy
// of compute instead of before it (r11's ring was collapsed by the
// compiler: VGPR stayed 72; JIT loads = ~1100cy/layer stall).

#define G 2

// ---- packed-FP32 asm helpers (weight broadcast via op_sel) ----
template<int HI>
__device__ __forceinline__ float2 pk_mul_b(float2 a, float2 w) {
    float2 d;
    if constexpr (HI)
        asm("v_pk_mul_f32 %0, %1, %2 op_sel:[0,1] op_sel_hi:[1,1]"
            : "=v"(d) : "v"(a), "v"(w));
    else
        asm("v_pk_mul_f32 %0, %1, %2 op_sel_hi:[1,0]"
            : "=v"(d) : "v"(a), "v"(w));
    return d;
}
template<int HI>
__device__ __forceinline__ float2 pk_fma_b(float2 a, float2 w, float2 c) {
    float2 d;
    if constexpr (HI)
        asm("v_pk_fma_f32 %0, %1, %2, %3 op_sel:[0,1,0] op_sel_hi:[1,1,1]"
            : "=v"(d) : "v"(a), "v"(w), "v"(c));
    else
        asm("v_pk_fma_f32 %0, %1, %2, %3 op_sel_hi:[1,0,1]"
            : "=v"(d) : "v"(a), "v"(w), "v"(c));
    return d;
}
__device__ __forceinline__ float2 pk_mul2(float2 a, float2 b) {
    float2 d;
    asm("v_pk_mul_f32 %0, %1, %2" : "=v"(d) : "v"(a), "v"(b));
    return d;
}
__device__ __forceinline__ float vexp2(float x) {   // 2^x on TRANS pipe
    float d;
    asm("v_exp_f32 %0, %1" : "=v"(d) : "v"(x));
    return d;
}

__device__ __forceinline__ float elu_f(float a) {
    return a > 0.0f ? a : (__expf(a) - 1.0f);
}

// ---- one slot of a scan layer, both rows packed; static recursion ----
template<int K, int I, int NW>
__device__ __forceinline__ void slot_run(float2 (&h)[K], const float2 (&w)[NW],
                                         float2 e0, float2 e1, float2 l2e) {
    if constexpr (I < K) {
        float2 x1, x2;
        if constexpr (I + 1 < K) x1 = h[I + 1]; else x1 = e0;
        if constexpr (I + 2 < K) x2 = h[I + 2];
        else if constexpr (I + 2 == K) x2 = e0;
        else x2 = e1;
        float2 acc = pk_mul_b<(3 * I + 2) & 1>(x2, w[(3 * I + 2) >> 1]);
        acc = pk_fma_b<(3 * I + 1) & 1>(x1, w[(3 * I + 1) >> 1], acc);
        acc = pk_fma_b<(3 * I) & 1>(h[I], w[(3 * I) >> 1], acc);
        float2 t = pk_mul2(acc, l2e);                 // a * log2(e)
        float ex = vexp2(t.x) - 1.0f;
        float ey = vexp2(t.y) - 1.0f;
        h[I].x = acc.x > 0.0f ? acc.x : ex;
        h[I].y = acc.y > 0.0f ? acc.y : ey;
        slot_run<K, I + 1, NW>(h, w, e0, e1, l2e);
    }
}

template<int K, int NW>
__device__ __forceinline__ void scan_layer_pk(float2 (&h)[K], const float2 (&w)[NW],
                                              float2 l2e) {
    float2 e0, e1;
    e0.x = __shfl_down(h[0].x, 1); e0.y = __shfl_down(h[0].y, 1);
    if constexpr (K >= 2) { e1.x = __shfl_down(h[1].x, 1); e1.y = __shfl_down(h[1].y, 1); }
    else                  { e1.x = __shfl_down(h[0].x, 2); e1.y = __shfl_down(h[0].y, 2); }
    slot_run<K, 0, NW>(h, w, e0, e1, l2e);
}

// ---- transposed-weight load: NC float4 -> 2*NC float2 pairs ----
template<int NC>
__device__ __forceinline__ void load_wt2(float2 (&w)[2 * NC], const float4* __restrict__ Tp,
                                         int lr) {
#pragma unroll
    for (int c = 0; c < NC; ++c) {
        float4 v = Tp[(size_t)lr * (NC * 64) + c * 64];
        w[2 * c]     = make_float2(v.x, v.y);
        w[2 * c + 1] = make_float2(v.z, v.w);
    }
}

// ---- scan phase: depth-2 pipeline, loads PINNED before compute via
//      sched_barrier(0). Unconditional l+2 prefetch overshoots <=1 layer
//      into the next phase's region / the final pad (never consumed). ----
template<int K, int NC, int NL>
__device__ __forceinline__ void scan_phase_pk(const float* __restrict__ Tphase,
                                              int lane, float2 (&h)[K], float2 l2e) {
    const float4* __restrict__ Tp = reinterpret_cast<const float4*>(Tphase) + lane;
    float2 wa[2 * NC], wb[2 * NC];
    load_wt2<NC>(wa, Tp, 0);
    int l = 0;
    for (; l + 2 <= NL; l += 2) {
        load_wt2<NC>(wb, Tp, l + 1);          // prefetch layer l+1
        __builtin_amdgcn_sched_barrier(0);    // loads must issue before compute
        scan_layer_pk<K>(h, wa, l2e);         // compute layer l
        load_wt2<NC>(wa, Tp, l + 2);          // prefetch layer l+2 (may overshoot)
        __builtin_amdgcn_sched_barrier(0);
        scan_layer_pk<K>(h, wb, l2e);         // compute layer l+1
    }
    if constexpr (NL % 2 == 1) scan_layer_pk<K>(h, wa, l2e);
}

// ---- state repack KA -> KB via wave-local LDS (both rows at once) ----
template<int KA, int KB>
__device__ __forceinline__ void repack_pk(float2 (&a)[KA], float2 (&n)[KB],
                                          float2* lds, int lane) {
    __syncthreads();
#pragma unroll
    for (int i = 0; i < KA; ++i) lds[KA * lane + i] = a[i];
    __syncthreads();
#pragma unroll
    for (int i = 0; i < KB; ++i) n[i] = lds[KB * lane + i];
    __syncthreads();
}

// ---- biased 3-tap layer, K=5 layout, zero-padded ends ----
__device__ __forceinline__ void stage2_pk(float2 (&h)[5], const float* __restrict__ Ws,
                                          const float* __restrict__ bs, int lane) {
#pragma unroll
    for (int i = 0; i < 5; ++i)
        if (5 * lane + i > 255) h[i] = make_float2(0.f, 0.f);
    float w0[5], w1[5], w2[5], bb[5];
#pragma unroll
    for (int i = 0; i < 5; ++i) {
        int j = 5 * lane + i;
        bool v = j < 256;
        w0[i] = v ? Ws[3 * j + 0] : 0.f;
        w1[i] = v ? Ws[3 * j + 1] : 0.f;
        w2[i] = v ? Ws[3 * j + 2] : 0.f;
        bb[i] = v ? bs[j] : 0.f;
    }
    float2 p, q;
    p.x = __shfl_up(h[4].x, 1); p.y = __shfl_up(h[4].y, 1);
    if (lane == 0) p = make_float2(0.f, 0.f);
    q.x = __shfl_down(h[0].x, 1); q.y = __shfl_down(h[0].y, 1);
    float2 y[5];
#pragma unroll
    for (int i = 0; i < 5; ++i) {
        float2 xm = (i == 0) ? p : h[i - 1];
        float2 xp = (i == 4) ? q : h[i + 1];
        float ax = fmaf(xm.x, w0[i], fmaf(h[i].x, w1[i], fmaf(xp.x, w2[i], bb[i])));
        float ay = fmaf(xm.y, w0[i], fmaf(h[i].y, w1[i], fmaf(xp.y, w2[i], bb[i])));
        y[i].x = elu_f(ax);
        y[i].y = elu_f(ay);
    }
#pragma unroll
    for (int i = 0; i < 5; ++i) h[i] = y[i];
}

// ---- final 10 logits + log-softmax for one row (K=1: position = lane) ----
__device__ __forceinline__ void emit_row(float v, const float* __restrict__ Wl,
                                         float* __restrict__ out, int row, int lane) {
    float n1 = __shfl_down(v, 1);
    float n2 = __shfl_down(v, 2);
    float lg = 0.0f;
    if (lane < 10)
        lg = fmaf(v, Wl[3 * lane], fmaf(n1, Wl[3 * lane + 1], n2 * Wl[3 * lane + 2]));
    float t = (lane < 10) ? lg : -1e30f;
#pragma unroll
    for (int d = 1; d < 16; d <<= 1) t = fmaxf(t, __shfl_xor(t, d));
    float e = (lane < 10) ? __expf(lg - t) : 0.0f;
    float s = e;
#pragma unroll
    for (int d = 1; d < 16; d <<= 1) s += __shfl_xor(s, d);
    float lse = t + __logf(s);
    if (lane < 10) out[(size_t)row * 10 + lane] = lg - lse;
}

// ---- transposed-weight layout (floats), fine-K ladder (same as r11) ----
//  ph  K NC  l0  nl  base          (scan1: W0 lstride 2346; scan2: W2 762)
//  0  13 10   0   7  0
//  1  12  9   7  32  17920
//  2  11  9  39  32  91648
//  3  10  8  71  32  165376
//  4   9  7 103  32  230912
//  5   8  6 135  32  288256
//  6   7  6 167  32  337408
//  7   6  5 199  32  386560
//  8   5  4 231  32  427520
//  9   4  3   0  31  460288
// 10   3  3  31  32  484096
// 11   2  2  63  32  508672
// 12   1  1  95  26  525056
#define T_TOTAL 531712   // floats written; alloc +512 pad for prefetch overshoot
#define T_ALLOC (T_TOTAL + 512)

__global__ __launch_bounds__(256)
void reorder_w(const float* __restrict__ W0, const float* __restrict__ W2,
               float* __restrict__ T) {
    int idx = blockIdx.x * 256 + threadIdx.x;
    if (idx >= T_ALLOC) return;
    if (idx >= T_TOTAL) { T[idx] = 0.0f; return; }   // pad: benign values
    int base, l0, K, NC, s1;
    if      (idx < 17920)  { base = 0;      l0 = 0;   K = 13; NC = 10; s1 = 1; }
    else if (idx < 91648)  { base = 17920;  l0 = 7;   K = 12; NC = 9;  s1 = 1; }
    else if (idx < 165376) { base = 91648;  l0 = 39;  K = 11; NC = 9;  s1 = 1; }
    else if (idx < 230912) { base = 165376; l0 = 71;  K = 10; NC = 8;  s1 = 1; }
    else if (idx < 288256) { base = 230912; l0 = 103; K = 9;  NC = 7;  s1 = 1; }
    else if (idx < 337408) { base = 288256; l0 = 135; K = 8;  NC = 6;  s1 = 1; }
    else if (idx < 386560) { base = 337408; l0 = 167; K = 7;  NC = 6;  s1 = 1; }
    else if (idx < 427520) { base = 386560; l0 = 199; K = 6;  NC = 5;  s1 = 1; }
    else if (idx < 460288) { base = 427520; l0 = 231; K = 5;  NC = 4;  s1 = 1; }
    else if (idx < 484096) { base = 460288; l0 = 0;   K = 4;  NC = 3;  s1 = 0; }
    else if (idx < 508672) { base = 484096; l0 = 31;  K = 3;  NC = 3;  s1 = 0; }
    else if (idx < 525056) { base = 508672; l0 = 63;  K = 2;  NC = 2;  s1 = 0; }
    else                   { base = 525056; l0 = 95;  K = 1;  NC = 1;  s1 = 0; }
    const float* Wsrc = s1 ? W0 : W2;
    int lstride = s1 ? 2346 : 762;
    int rel  = idx - base;
    int perL = NC * 256;
    int lr   = rel / perL;
    int r2   = rel - lr * perL;
    int c    = r2 >> 8;
    int ln   = (r2 >> 2) & 63;
    int f    = r2 & 3;
    int elem = 4 * c + f;
    float v = 0.0f;
    if (elem < 3 * K) {
        int b = 3 * K * ln;
        if (b + 3 * K > lstride) b = lstride - 3 * K;  // clamped lanes are all-dead
        v = Wsrc[(size_t)(l0 + lr) * lstride + b + elem];
    }
    T[idx] = v;
}

// ---- main kernel (packed, pinned depth-2 pipeline) ----
__global__ __launch_bounds__(64)
void pg_kernel_pk(const float* __restrict__ x,  const float* __restrict__ Ws,
                  const float* __restrict__ bs, const float* __restrict__ Wlast,
                  const float* __restrict__ T,  float* __restrict__ out)
{
    __shared__ float2 lds2[13 * 64];        // repack scratch, 6.5 KB
    const int lane = threadIdx.x;
    const int rowA = blockIdx.x * G;
    const int rowB = rowA + 1;
    const float2 l2e = make_float2(1.44269504088896340736f, 1.44269504088896340736f);

    float2 h13[13];
#pragma unroll
    for (int i = 0; i < 13; ++i) {
        int p = 13 * lane + i;
        h13[i].x = (p < 784) ? x[(size_t)rowA * 784 + p] : 0.0f;
        h13[i].y = (p < 784) ? x[(size_t)rowB * 784 + p] : 0.0f;
    }

    // ---- scan 1 (263 layers) ----
    scan_phase_pk<13, 10, 7>(T + 0,       lane, h13, l2e);
    float2 h12[12]; repack_pk<13, 12>(h13, h12, lds2, lane);
    scan_phase_pk<12, 9, 32>(T + 17920,   lane, h12, l2e);
    float2 h11[11]; repack_pk<12, 11>(h12, h11, lds2, lane);
    scan_phase_pk<11, 9, 32>(T + 91648,   lane, h11, l2e);
    float2 h10[10]; repack_pk<11, 10>(h11, h10, lds2, lane);
    scan_phase_pk<10, 8, 32>(T + 165376,  lane, h10, l2e);
    float2 h9[9];   repack_pk<10, 9>(h10, h9, lds2, lane);
    scan_phase_pk<9, 7, 32>(T + 230912,   lane, h9, l2e);
    float2 h8[8];   repack_pk<9, 8>(h9, h8, lds2, lane);
    scan_phase_pk<8, 6, 32>(T + 288256,   lane, h8, l2e);
    float2 h7[7];   repack_pk<8, 7>(h8, h7, lds2, lane);
    scan_phase_pk<7, 6, 32>(T + 337408,   lane, h7, l2e);
    float2 h6[6];   repack_pk<7, 6>(h7, h6, lds2, lane);
    scan_phase_pk<6, 5, 32>(T + 386560,   lane, h6, l2e);
    float2 h5[5];   repack_pk<6, 5>(h6, h5, lds2, lane);
    scan_phase_pk<5, 4, 32>(T + 427520,   lane, h5, l2e);

    // ---- biased layer (width 256) ----
    stage2_pk(h5, Ws, bs, lane);

    // ---- scan 2 (121 layers) ----
    float2 h4[4];   repack_pk<5, 4>(h5, h4, lds2, lane);
    scan_phase_pk<4, 3, 31>(T + 460288,   lane, h4, l2e);
    float2 h3[3];   repack_pk<4, 3>(h4, h3, lds2, lane);
    scan_phase_pk<3, 3, 32>(T + 484096,   lane, h3, l2e);
    float2 h2[2];   repack_pk<3, 2>(h3, h2, lds2, lane);
    scan_phase_pk<2, 2, 32>(T + 508672,   lane, h2, l2e);
    float2 h1[1];   repack_pk<2, 1>(h2, h1, lds2, lane);
    scan_phase_pk<1, 1, 26>(T + 525056,   lane, h1, l2e);

    emit_row(h1[0].x, Wlast, out, rowA, lane);
    emit_row(h1[0].y, Wlast, out, rowB, lane);
}

// ---- scalar fallback (direct gather) used only if ws too small ----
template<int K>
__device__ __forceinline__ void scan_layer_s(float (&h)[K], const float (&w)[3 * K]) {
    float e0 = __shfl_down(h[0], 1);
    float e1;
    if constexpr (K >= 2) e1 = __shfl_down(h[1], 1);
    else                  e1 = __shfl_down(h[0], 2);
#pragma unroll
    for (int i = 0; i < K; ++i) {
        float x1 = (i + 1 < K) ? h[i + 1] : e0;
        float x2 = (i + 2 < K) ? h[i + 2] : ((i + 2 == K) ? e0 : e1);
        float a = fmaf(h[i], w[3 * i], fmaf(x1, w[3 * i + 1], x2 * w[3 * i + 2]));
        h[i] = elu_f(a);
    }
}
template<int K>
__device__ __forceinline__ void scan_phase_s(const float* __restrict__ W, int lstride,
                                             int l0, int l1, int lane,
                                             float (&hA)[K], float (&hB)[K]) {
    int base = 3 * K * lane;
    if (base + 3 * K > lstride) base = lstride - 3 * K;
    const float* __restrict__ Wp = W + (size_t)l0 * lstride + base;
    float wa[3 * K];
    for (int l = l0; l < l1; ++l) {
#pragma unroll
        for (int j = 0; j < 3 * K; ++j) wa[j] = Wp[j];
        scan_layer_s<K>(hA, wa);
        scan_layer_s<K>(hB, wa);
        Wp += lstride;
    }
}
template<int KA, int KB>
__device__ __forceinline__ void repack_s(float (&aA)[KA], float (&aB)[KA],
                                         float (&nA)[KB], float (&nB)[KB],
                                         float* lds, int lane) {
    __syncthreads();
#pragma unroll
    for (int i = 0; i < KA; ++i) lds[KA * lane + i] = aA[i];
    __syncthreads();
#pragma unroll
    for (int i = 0; i < KB; ++i) nA[i] = lds[KB * lane + i];
    __syncthreads();
#pragma unroll
    for (int i = 0; i < KA; ++i) lds[KA * lane + i] = aB[i];
    __syncthreads();
#pragma unroll
    for (int i = 0; i < KB; ++i) nB[i] = lds[KB * lane + i];
    __syncthreads();
}
__global__ __launch_bounds__(64)
void pg_kernel_d(const float* __restrict__ x,  const float* __restrict__ W0,
                 const float* __restrict__ Ws, const float* __restrict__ bs,
                 const float* __restrict__ W2, const float* __restrict__ Wlast,
                 float* __restrict__ out)
{
    __shared__ float lds[13 * 64];
    const int lane = threadIdx.x;
    const int rowA = blockIdx.x * 2;
    const int rowB = rowA + 1;
    float a13[13], b13[13];
#pragma unroll
    for (int i = 0; i < 13; ++i) {
        int p = 13 * lane + i;
        a13[i] = (p < 784) ? x[(size_t)rowA * 784 + p] : 0.0f;
        b13[i] = (p < 784) ? x[(size_t)rowB * 784 + p] : 0.0f;
    }
    scan_phase_s<13>(W0, 2346, 0, 71, lane, a13, b13);
    float a10[10], b10[10]; repack_s<13, 10>(a13, b13, a10, b10, lds, lane);
    scan_phase_s<10>(W0, 2346, 71, 167, lane, a10, b10);
    float a7[7], b7[7];     repack_s<10, 7>(a10, b10, a7, b7, lds, lane);
    scan_phase_s<7>(W0, 2346, 167, 231, lane, a7, b7);
    float a5[5], b5[5];     repack_s<7, 5>(a7, b7, a5, b5, lds, lane);
    scan_phase_s<5>(W0, 2346, 231, 263, lane, a5, b5);
    {
        float2 hp[5];
#pragma unroll
        for (int i = 0; i < 5; ++i) hp[i] = make_float2(a5[i], b5[i]);
        stage2_pk(hp, Ws, bs, lane);
#pragma unroll
        for (int i = 0; i < 5; ++i) { a5[i] = hp[i].x; b5[i] = hp[i].y; }
    }
    float a4[4], b4[4];     repack_s<5, 4>(a5, b5, a4, b4, lds, lane);
    scan_phase_s<4>(W2, 762, 0, 31, lane, a4, b4);
    float a3[3], b3[3];     repack_s<4, 3>(a4, b4, a3, b3, lds, lane);
    scan_phase_s<3>(W2, 762, 31, 63, lane, a3, b3);
    float a2_[2], b2_[2];   repack_s<3, 2>(a3, b3, a2_, b2_, lds, lane);
    scan_phase_s<2>(W2, 762, 63, 95, lane, a2_, b2_);
    float a1[1], b1[1];     repack_s<2, 1>(a2_, b2_, a1, b1, lds, lane);
    scan_phase_s<1>(W2, 762, 95, 121, lane, a1, b1);
    emit_row(a1[0], Wlast, out, rowA, lane);
    emit_row(b1[0], Wlast, out, rowB, lane);
}

extern "C" void kernel_launch(void* const* d_in, const int* in_sizes, int n_in,
                              void* d_out, int out_size, void* d_ws, size_t ws_size,
                              hipStream_t stream) {
    const float* x     = (const float*)d_in[0];
    const float* W0    = (const float*)d_in[1];
    const float* Ws    = (const float*)d_in[2];
    const float* bs    = (const float*)d_in[3];
    const float* W2    = (const float*)d_in[4];
    const float* Wlast = (const float*)d_in[5];
    float* out = (float*)d_out;

    if (ws_size >= (size_t)T_ALLOC * sizeof(float)) {
        float* T = (float*)d_ws;
        reorder_w<<<(T_ALLOC + 255) / 256, 256, 0, stream>>>(W0, W2, T);
        pg_kernel_pk<<<4096 / G, 64, 0, stream>>>(x, Ws, bs, Wlast, T, out);
    } else {
        pg_kernel_d<<<2048, 64, 0, stream>>>(x, W0, Ws, bs, W2, Wlast, out);
    }
}